// Round 7
// baseline (708.557 us; speedup 1.0000x reference)
//
#include <hip/hip_runtime.h>
#include <math.h>

// ContextualLoss via MFMA bf16.
// X,T = reshape(50,16384)[10:50]; S = Xn^T Tn (K=40 padded to 64, bf16 MFMA);
// per input-column i: m=min_j S, M=max_j S, Z=sum_j exp((1-S/(m+eps))/h);
// CXmax_i = max(w(m),w(M))/Z (w monotone in S); loss = -log(max_i CXmax_i).
//
// R7 change: JS 16->32 (8 waves/SIMD instead of 4) + __launch_bounds__(256,8)
// to pin VGPR <= 64. Hot kernels were stall-bound (VALUBusy 64%, Occ 40%).

#define NCOL   16384
#define KDIM   40
#define KPAD   64
#define ROW0   10
#define EPSILON 1e-5f
#define COS_EPS 1e-8f
#define Q5L2E   7.2134752044448169f   // 5 * log2(e)  (1/h = 5)
#define JS      32                    // j slices
#define JSL     (NCOL / JS)           // 512 j per slice
#define JT_PER  (JSL / 16)            // 32 16-wide j tiles per wave

typedef __attribute__((ext_vector_type(8))) short bf16x8;
typedef __attribute__((ext_vector_type(4))) float f32x4;

static __device__ __forceinline__ unsigned short f2bf(float f) {
    unsigned u = __float_as_uint(f);           // RNE float->bf16
    u += 0x7FFFu + ((u >> 16) & 1u);
    return (unsigned short)(u >> 16);
}

// ---------------- kernel 1: mu + column normalize + bf16 pack ----------------
__global__ __launch_bounds__(256) void ctx_norm_kernel(
        const float* __restrict__ inp, const float* __restrict__ tgt,
        short* __restrict__ xb, short* __restrict__ tb) {
    int n = blockIdx.x * 256 + threadIdx.x;
    float t[KDIM], x[KDIM];
    float mu = 0.f;
#pragma unroll
    for (int r = 0; r < KDIM; ++r) { t[r] = tgt[(ROW0 + r) * NCOL + n]; mu += t[r]; }
    mu *= (1.0f / KDIM);
    float nt = 0.f;
#pragma unroll
    for (int r = 0; r < KDIM; ++r) { t[r] -= mu; nt = fmaf(t[r], t[r], nt); }
    float rnt = 1.0f / fmaxf(sqrtf(nt), COS_EPS);
    float nx = 0.f;
#pragma unroll
    for (int r = 0; r < KDIM; ++r) {
        x[r] = inp[(ROW0 + r) * NCOL + n] - mu;
        nx = fmaf(x[r], x[r], nx);
    }
    float rnx = 1.0f / fmaxf(sqrtf(nx), COS_EPS);

    short* to = tb + (size_t)n * KPAD;
    short* xo = xb + (size_t)n * KPAD;
#pragma unroll
    for (int q = 0; q < KDIM / 4; ++q) {        // q = 0..9: data
        ushort4 wt, wx;
        wt.x = f2bf(t[4*q+0] * rnt); wt.y = f2bf(t[4*q+1] * rnt);
        wt.z = f2bf(t[4*q+2] * rnt); wt.w = f2bf(t[4*q+3] * rnt);
        wx.x = f2bf(x[4*q+0] * rnx); wx.y = f2bf(x[4*q+1] * rnx);
        wx.z = f2bf(x[4*q+2] * rnx); wx.w = f2bf(x[4*q+3] * rnx);
        *reinterpret_cast<ushort4*>(to + 4*q) = wt;
        *reinterpret_cast<ushort4*>(xo + 4*q) = wx;
    }
    ushort4 z = {0, 0, 0, 0};
#pragma unroll
    for (int q = KDIM / 4; q < KPAD / 4; ++q) { // q = 10..15: zero pad
        *reinterpret_cast<ushort4*>(to + 4*q) = z;
        *reinterpret_cast<ushort4*>(xo + 4*q) = z;
    }
}

// ---------------- kernel 2: MFMA row min/max over a j slice ----------------
// grid (64, JS), 256 thr = 4 waves. Wave owns 64 i-rows (4 MFMA M-subtiles),
// scans JSL j's. A-frags register-resident; B-frags straight from global
// (wave-span 1KB, L1/L2-hit). C/D layout: col=lane&15, row=(lane>>4)*4+reg.
__global__ __launch_bounds__(256, 8) void ctx_stats_kernel(
        const short* __restrict__ xb, const short* __restrict__ tb,
        float* __restrict__ pmin, float* __restrict__ pmax) {
    const int tid = threadIdx.x;
    const int wave = tid >> 6, l = tid & 63;
    const int la = l & 15, g = l >> 4;
    const int ibase = blockIdx.x * 256 + wave * 64;
    const int js = blockIdx.y;

    bf16x8 a[4][2];
#pragma unroll
    for (int mi = 0; mi < 4; ++mi)
#pragma unroll
        for (int ks = 0; ks < 2; ++ks)
            a[mi][ks] = *reinterpret_cast<const bf16x8*>(
                xb + (size_t)(ibase + mi * 16 + la) * KPAD + ks * 32 + g * 8);

    float vmn[4][4], vmx[4][4];
#pragma unroll
    for (int mi = 0; mi < 4; ++mi)
#pragma unroll
        for (int r = 0; r < 4; ++r) { vmn[mi][r] = 3.4e38f; vmx[mi][r] = -3.4e38f; }

    const f32x4 zero4 = {0.f, 0.f, 0.f, 0.f};
    const short* bp = tb + (size_t)(js * JSL + la) * KPAD + g * 8;
#pragma unroll 2
    for (int jt = 0; jt < JT_PER; ++jt) {
        bf16x8 b0 = *reinterpret_cast<const bf16x8*>(bp);
        bf16x8 b1 = *reinterpret_cast<const bf16x8*>(bp + 32);
        bp += 16 * KPAD;
#pragma unroll
        for (int mi = 0; mi < 4; ++mi) {
            f32x4 acc = __builtin_amdgcn_mfma_f32_16x16x32_bf16(a[mi][0], b0, zero4, 0, 0, 0);
            acc = __builtin_amdgcn_mfma_f32_16x16x32_bf16(a[mi][1], b1, acc, 0, 0, 0);
#pragma unroll
            for (int r = 0; r < 4; ++r) {
                vmn[mi][r] = fminf(vmn[mi][r], acc[r]);
                vmx[mi][r] = fmaxf(vmx[mi][r], acc[r]);
            }
        }
    }
    // reduce over the 16 column-lanes of each 16-lane group
#pragma unroll
    for (int off = 1; off < 16; off <<= 1)
#pragma unroll
        for (int mi = 0; mi < 4; ++mi)
#pragma unroll
            for (int r = 0; r < 4; ++r) {
                vmn[mi][r] = fminf(vmn[mi][r], __shfl_xor(vmn[mi][r], off, 64));
                vmx[mi][r] = fmaxf(vmx[mi][r], __shfl_xor(vmx[mi][r], off, 64));
            }
    if (la == 0) {
#pragma unroll
        for (int mi = 0; mi < 4; ++mi)
#pragma unroll
            for (int r = 0; r < 4; ++r) {
                int row = ibase + mi * 16 + g * 4 + r;
                pmin[js * NCOL + row] = vmn[mi][r];
                pmax[js * NCOL + row] = vmx[mi][r];
            }
    }
}

// ---------------- kernel 3: fold JS partials -> final row min/max ----------------
__global__ __launch_bounds__(256) void ctx_fold_kernel(
        const float* __restrict__ pmin, const float* __restrict__ pmax,
        float* __restrict__ rmin, float* __restrict__ rmax) {
    int i = blockIdx.x * 256 + threadIdx.x;
    float m = pmin[i], M = pmax[i];
#pragma unroll
    for (int s = 1; s < JS; ++s) {
        m = fminf(m, pmin[s * NCOL + i]);
        M = fmaxf(M, pmax[s * NCOL + i]);
    }
    rmin[i] = m; rmax[i] = M;
}

// ---------------- kernel 4: MFMA row sum of exp over a j slice ----------------
// w = exp((1-S*c)/h) = exp2(fma(S, -Q5L2E*c, Q5L2E)), c = 1/(m+eps) per row.
__global__ __launch_bounds__(256, 8) void ctx_sumexp_kernel(
        const short* __restrict__ xb, const short* __restrict__ tb,
        const float* __restrict__ rmin, float* __restrict__ psum) {
    const int tid = threadIdx.x;
    const int wave = tid >> 6, l = tid & 63;
    const int la = l & 15, g = l >> 4;
    const int ibase = blockIdx.x * 256 + wave * 64;
    const int js = blockIdx.y;

    bf16x8 a[4][2];
#pragma unroll
    for (int mi = 0; mi < 4; ++mi)
#pragma unroll
        for (int ks = 0; ks < 2; ++ks)
            a[mi][ks] = *reinterpret_cast<const bf16x8*>(
                xb + (size_t)(ibase + mi * 16 + la) * KPAD + ks * 32 + g * 8);

    float p[4][4], zs[4][4];
#pragma unroll
    for (int mi = 0; mi < 4; ++mi)
#pragma unroll
        for (int r = 0; r < 4; ++r) {
            int row = ibase + mi * 16 + g * 4 + r;
            float c = 1.0f / (rmin[row] + EPSILON);
            p[mi][r] = -Q5L2E * c;
            zs[mi][r] = 0.f;
        }

    const f32x4 zero4 = {0.f, 0.f, 0.f, 0.f};
    const short* bp = tb + (size_t)(js * JSL + la) * KPAD + g * 8;
#pragma unroll 2
    for (int jt = 0; jt < JT_PER; ++jt) {
        bf16x8 b0 = *reinterpret_cast<const bf16x8*>(bp);
        bf16x8 b1 = *reinterpret_cast<const bf16x8*>(bp + 32);
        bp += 16 * KPAD;
#pragma unroll
        for (int mi = 0; mi < 4; ++mi) {
            f32x4 acc = __builtin_amdgcn_mfma_f32_16x16x32_bf16(a[mi][0], b0, zero4, 0, 0, 0);
            acc = __builtin_amdgcn_mfma_f32_16x16x32_bf16(a[mi][1], b1, acc, 0, 0, 0);
#pragma unroll
            for (int r = 0; r < 4; ++r)
                zs[mi][r] += exp2f(fmaf(acc[r], p[mi][r], Q5L2E));
        }
    }
#pragma unroll
    for (int off = 1; off < 16; off <<= 1)
#pragma unroll
        for (int mi = 0; mi < 4; ++mi)
#pragma unroll
            for (int r = 0; r < 4; ++r)
                zs[mi][r] += __shfl_xor(zs[mi][r], off, 64);
    if (la == 0) {
#pragma unroll
        for (int mi = 0; mi < 4; ++mi)
#pragma unroll
            for (int r = 0; r < 4; ++r) {
                int row = ibase + mi * 16 + g * 4 + r;
                psum[js * NCOL + row] = zs[mi][r];
            }
    }
}

// ---------------- kernel 5: per-row CX-max, per-block max ----------------
__global__ __launch_bounds__(256) void ctx_reduce_kernel(
        const float* __restrict__ rmin, const float* __restrict__ rmax,
        const float* __restrict__ psum, float* __restrict__ blkmax) {
    int tid = threadIdx.x;
    int i = blockIdx.x * 256 + tid;
    float m = rmin[i], M = rmax[i], Z = psum[i];
#pragma unroll
    for (int s = 1; s < JS; ++s) Z += psum[s * NCOL + i];
    float c = 1.0f / (m + EPSILON);
    float w1 = exp2f(fmaf(M, -Q5L2E * c, Q5L2E));
    float w2 = exp2f(fmaf(m, -Q5L2E * c, Q5L2E));
    float best = fmaxf(w1, w2) / Z;   // CX strictly positive

    for (int off = 32; off > 0; off >>= 1)
        best = fmaxf(best, __shfl_down(best, off, 64));
    __shared__ float red[4];
    if ((tid & 63) == 0) red[tid >> 6] = best;
    __syncthreads();
    if (tid == 0)
        blkmax[blockIdx.x] = fmaxf(fmaxf(red[0], red[1]), fmaxf(red[2], red[3]));
}

// ---------------- kernel 6: 64 -> 1, -log ----------------
__global__ void ctx_loss_kernel(const float* __restrict__ blkmax,
                                float* __restrict__ out) {
    int tid = threadIdx.x;       // one wave of 64
    float best = blkmax[tid];
    for (int off = 32; off > 0; off >>= 1)
        best = fmaxf(best, __shfl_down(best, off, 64));
    if (tid == 0) out[0] = -logf(best);
}

extern "C" void kernel_launch(void* const* d_in, const int* in_sizes, int n_in,
                              void* d_out, int out_size, void* d_ws, size_t ws_size,
                              hipStream_t stream) {
    const float* inp = (const float*)d_in[0];
    const float* tgt = (const float*)d_in[1];
    float* out = (float*)d_out;

    // ws layout (bytes):
    //   xb     bf16 [16384][64]  2 MB
    //   tb     bf16 [16384][64]  2 MB
    //   pmin   f32  [32][16384]  2 MB
    //   pmax   f32  [32][16384]  2 MB
    //   psum   f32  [32][16384]  2 MB
    //   rmin   f32  [16384]      64 KB
    //   rmax   f32  [16384]      64 KB
    //   blkmax f32  [64]
    char* base = (char*)d_ws;
    short* xb     = (short*)(base);
    short* tb     = (short*)(base + (size_t)2 * NCOL * KPAD);           // +2MB
    float* pmin   = (float*)(base + (size_t)4 * NCOL * KPAD);           // +4MB
    float* pmax   = pmin + (size_t)JS * NCOL;
    float* psum   = pmax + (size_t)JS * NCOL;
    float* rmin   = psum + (size_t)JS * NCOL;
    float* rmax   = rmin + NCOL;
    float* blkmax = rmax + NCOL;

    dim3 grid2(NCOL / 256, JS);
    ctx_norm_kernel  <<<NCOL / 256, 256, 0, stream>>>(inp, tgt, xb, tb);
    ctx_stats_kernel <<<grid2, 256, 0, stream>>>(xb, tb, pmin, pmax);
    ctx_fold_kernel  <<<NCOL / 256, 256, 0, stream>>>(pmin, pmax, rmin, rmax);
    ctx_sumexp_kernel<<<grid2, 256, 0, stream>>>(xb, tb, rmin, psum);
    ctx_reduce_kernel<<<NCOL / 256, 256, 0, stream>>>(rmin, rmax, psum, blkmax);
    ctx_loss_kernel  <<<1, 64, 0, stream>>>(blkmax, out);
}

// Round 8
// 185.681 us; speedup vs baseline: 3.8160x; 3.8160x over previous
//
#include <hip/hip_runtime.h>
#include <math.h>

// ContextualLoss via MFMA bf16.
// X,T = reshape(50,16384)[10:50]; S = Xn^T Tn (K=40 padded to 64, bf16 MFMA);
// per input-column i: m=min_j S, M=max_j S, Z=sum_j exp((1-S/(m+eps))/h);
// CXmax_i = max(w(m),w(M))/Z (w monotone in S); loss = -log(max_i CXmax_i).
//
// R8: JS=32 (2048 blocks -> 8 blocks/CU -> 8 waves/SIMD) with
// __launch_bounds__(256,4). R7's (256,8) pin forced VGPR 64->32 and spilled
// to scratch (950MB fetch/dispatch) -- the live set needs ~64 VGPRs, so the
// occupancy must come from grid size, not from an allocator pin.

#define NCOL   16384
#define KDIM   40
#define KPAD   64
#define ROW0   10
#define EPSILON 1e-5f
#define COS_EPS 1e-8f
#define Q5L2E   7.2134752044448169f   // 5 * log2(e)  (1/h = 5)
#define JS      32                    // j slices
#define JSL     (NCOL / JS)           // 512 j per slice
#define JT_PER  (JSL / 16)            // 32 16-wide j tiles per wave

typedef __attribute__((ext_vector_type(8))) short bf16x8;
typedef __attribute__((ext_vector_type(4))) float f32x4;

static __device__ __forceinline__ unsigned short f2bf(float f) {
    unsigned u = __float_as_uint(f);           // RNE float->bf16
    u += 0x7FFFu + ((u >> 16) & 1u);
    return (unsigned short)(u >> 16);
}

// ---------------- kernel 1: mu + column normalize + bf16 pack ----------------
__global__ __launch_bounds__(256) void ctx_norm_kernel(
        const float* __restrict__ inp, const float* __restrict__ tgt,
        short* __restrict__ xb, short* __restrict__ tb) {
    int n = blockIdx.x * 256 + threadIdx.x;
    float t[KDIM], x[KDIM];
    float mu = 0.f;
#pragma unroll
    for (int r = 0; r < KDIM; ++r) { t[r] = tgt[(ROW0 + r) * NCOL + n]; mu += t[r]; }
    mu *= (1.0f / KDIM);
    float nt = 0.f;
#pragma unroll
    for (int r = 0; r < KDIM; ++r) { t[r] -= mu; nt = fmaf(t[r], t[r], nt); }
    float rnt = 1.0f / fmaxf(sqrtf(nt), COS_EPS);
    float nx = 0.f;
#pragma unroll
    for (int r = 0; r < KDIM; ++r) {
        x[r] = inp[(ROW0 + r) * NCOL + n] - mu;
        nx = fmaf(x[r], x[r], nx);
    }
    float rnx = 1.0f / fmaxf(sqrtf(nx), COS_EPS);

    short* to = tb + (size_t)n * KPAD;
    short* xo = xb + (size_t)n * KPAD;
#pragma unroll
    for (int q = 0; q < KDIM / 4; ++q) {        // q = 0..9: data
        ushort4 wt, wx;
        wt.x = f2bf(t[4*q+0] * rnt); wt.y = f2bf(t[4*q+1] * rnt);
        wt.z = f2bf(t[4*q+2] * rnt); wt.w = f2bf(t[4*q+3] * rnt);
        wx.x = f2bf(x[4*q+0] * rnx); wx.y = f2bf(x[4*q+1] * rnx);
        wx.z = f2bf(x[4*q+2] * rnx); wx.w = f2bf(x[4*q+3] * rnx);
        *reinterpret_cast<ushort4*>(to + 4*q) = wt;
        *reinterpret_cast<ushort4*>(xo + 4*q) = wx;
    }
    ushort4 z = {0, 0, 0, 0};
#pragma unroll
    for (int q = KDIM / 4; q < KPAD / 4; ++q) { // q = 10..15: zero pad
        *reinterpret_cast<ushort4*>(to + 4*q) = z;
        *reinterpret_cast<ushort4*>(xo + 4*q) = z;
    }
}

// ---------------- kernel 2: MFMA row min/max over a j slice ----------------
// grid (64, JS), 256 thr = 4 waves. Wave owns 64 i-rows (4 MFMA M-subtiles),
// scans JSL j's. A-frags register-resident; B-frags straight from global
// (wave-span 1KB, L1/L2-hit). C/D layout: col=lane&15, row=(lane>>4)*4+reg.
__global__ __launch_bounds__(256, 4) void ctx_stats_kernel(
        const short* __restrict__ xb, const short* __restrict__ tb,
        float* __restrict__ pmin, float* __restrict__ pmax) {
    const int tid = threadIdx.x;
    const int wave = tid >> 6, l = tid & 63;
    const int la = l & 15, g = l >> 4;
    const int ibase = blockIdx.x * 256 + wave * 64;
    const int js = blockIdx.y;

    bf16x8 a[4][2];
#pragma unroll
    for (int mi = 0; mi < 4; ++mi)
#pragma unroll
        for (int ks = 0; ks < 2; ++ks)
            a[mi][ks] = *reinterpret_cast<const bf16x8*>(
                xb + (size_t)(ibase + mi * 16 + la) * KPAD + ks * 32 + g * 8);

    float vmn[4][4], vmx[4][4];
#pragma unroll
    for (int mi = 0; mi < 4; ++mi)
#pragma unroll
        for (int r = 0; r < 4; ++r) { vmn[mi][r] = 3.4e38f; vmx[mi][r] = -3.4e38f; }

    const f32x4 zero4 = {0.f, 0.f, 0.f, 0.f};
    const short* bp = tb + (size_t)(js * JSL + la) * KPAD + g * 8;
#pragma unroll 2
    for (int jt = 0; jt < JT_PER; ++jt) {
        bf16x8 b0 = *reinterpret_cast<const bf16x8*>(bp);
        bf16x8 b1 = *reinterpret_cast<const bf16x8*>(bp + 32);
        bp += 16 * KPAD;
#pragma unroll
        for (int mi = 0; mi < 4; ++mi) {
            f32x4 acc = __builtin_amdgcn_mfma_f32_16x16x32_bf16(a[mi][0], b0, zero4, 0, 0, 0);
            acc = __builtin_amdgcn_mfma_f32_16x16x32_bf16(a[mi][1], b1, acc, 0, 0, 0);
#pragma unroll
            for (int r = 0; r < 4; ++r) {
                vmn[mi][r] = fminf(vmn[mi][r], acc[r]);
                vmx[mi][r] = fmaxf(vmx[mi][r], acc[r]);
            }
        }
    }
    // reduce over the 16 column-lanes of each 16-lane group
#pragma unroll
    for (int off = 1; off < 16; off <<= 1)
#pragma unroll
        for (int mi = 0; mi < 4; ++mi)
#pragma unroll
            for (int r = 0; r < 4; ++r) {
                vmn[mi][r] = fminf(vmn[mi][r], __shfl_xor(vmn[mi][r], off, 64));
                vmx[mi][r] = fmaxf(vmx[mi][r], __shfl_xor(vmx[mi][r], off, 64));
            }
    if (la == 0) {
#pragma unroll
        for (int mi = 0; mi < 4; ++mi)
#pragma unroll
            for (int r = 0; r < 4; ++r) {
                int row = ibase + mi * 16 + g * 4 + r;
                pmin[js * NCOL + row] = vmn[mi][r];
                pmax[js * NCOL + row] = vmx[mi][r];
            }
    }
}

// ---------------- kernel 3: fold JS partials -> final row min/max ----------------
__global__ __launch_bounds__(256) void ctx_fold_kernel(
        const float* __restrict__ pmin, const float* __restrict__ pmax,
        float* __restrict__ rmin, float* __restrict__ rmax) {
    int i = blockIdx.x * 256 + threadIdx.x;
    float m = pmin[i], M = pmax[i];
#pragma unroll
    for (int s = 1; s < JS; ++s) {
        m = fminf(m, pmin[s * NCOL + i]);
        M = fmaxf(M, pmax[s * NCOL + i]);
    }
    rmin[i] = m; rmax[i] = M;
}

// ---------------- kernel 4: MFMA row sum of exp over a j slice ----------------
// w = exp((1-S*c)/h) = exp2(fma(S, -Q5L2E*c, Q5L2E)), c = 1/(m+eps) per row.
__global__ __launch_bounds__(256, 4) void ctx_sumexp_kernel(
        const short* __restrict__ xb, const short* __restrict__ tb,
        const float* __restrict__ rmin, float* __restrict__ psum) {
    const int tid = threadIdx.x;
    const int wave = tid >> 6, l = tid & 63;
    const int la = l & 15, g = l >> 4;
    const int ibase = blockIdx.x * 256 + wave * 64;
    const int js = blockIdx.y;

    bf16x8 a[4][2];
#pragma unroll
    for (int mi = 0; mi < 4; ++mi)
#pragma unroll
        for (int ks = 0; ks < 2; ++ks)
            a[mi][ks] = *reinterpret_cast<const bf16x8*>(
                xb + (size_t)(ibase + mi * 16 + la) * KPAD + ks * 32 + g * 8);

    float p[4][4], zs[4][4];
#pragma unroll
    for (int mi = 0; mi < 4; ++mi)
#pragma unroll
        for (int r = 0; r < 4; ++r) {
            int row = ibase + mi * 16 + g * 4 + r;
            float c = 1.0f / (rmin[row] + EPSILON);
            p[mi][r] = -Q5L2E * c;
            zs[mi][r] = 0.f;
        }

    const f32x4 zero4 = {0.f, 0.f, 0.f, 0.f};
    const short* bp = tb + (size_t)(js * JSL + la) * KPAD + g * 8;
#pragma unroll 2
    for (int jt = 0; jt < JT_PER; ++jt) {
        bf16x8 b0 = *reinterpret_cast<const bf16x8*>(bp);
        bf16x8 b1 = *reinterpret_cast<const bf16x8*>(bp + 32);
        bp += 16 * KPAD;
#pragma unroll
        for (int mi = 0; mi < 4; ++mi) {
            f32x4 acc = __builtin_amdgcn_mfma_f32_16x16x32_bf16(a[mi][0], b0, zero4, 0, 0, 0);
            acc = __builtin_amdgcn_mfma_f32_16x16x32_bf16(a[mi][1], b1, acc, 0, 0, 0);
#pragma unroll
            for (int r = 0; r < 4; ++r)
                zs[mi][r] += exp2f(fmaf(acc[r], p[mi][r], Q5L2E));
        }
    }
#pragma unroll
    for (int off = 1; off < 16; off <<= 1)
#pragma unroll
        for (int mi = 0; mi < 4; ++mi)
#pragma unroll
            for (int r = 0; r < 4; ++r)
                zs[mi][r] += __shfl_xor(zs[mi][r], off, 64);
    if (la == 0) {
#pragma unroll
        for (int mi = 0; mi < 4; ++mi)
#pragma unroll
            for (int r = 0; r < 4; ++r) {
                int row = ibase + mi * 16 + g * 4 + r;
                psum[js * NCOL + row] = zs[mi][r];
            }
    }
}

// ---------------- kernel 5: per-row CX-max, per-block max ----------------
__global__ __launch_bounds__(256) void ctx_reduce_kernel(
        const float* __restrict__ rmin, const float* __restrict__ rmax,
        const float* __restrict__ psum, float* __restrict__ blkmax) {
    int tid = threadIdx.x;
    int i = blockIdx.x * 256 + tid;
    float m = rmin[i], M = rmax[i], Z = psum[i];
#pragma unroll
    for (int s = 1; s < JS; ++s) Z += psum[s * NCOL + i];
    float c = 1.0f / (m + EPSILON);
    float w1 = exp2f(fmaf(M, -Q5L2E * c, Q5L2E));
    float w2 = exp2f(fmaf(m, -Q5L2E * c, Q5L2E));
    float best = fmaxf(w1, w2) / Z;   // CX strictly positive

    for (int off = 32; off > 0; off >>= 1)
        best = fmaxf(best, __shfl_down(best, off, 64));
    __shared__ float red[4];
    if ((tid & 63) == 0) red[tid >> 6] = best;
    __syncthreads();
    if (tid == 0)
        blkmax[blockIdx.x] = fmaxf(fmaxf(red[0], red[1]), fmaxf(red[2], red[3]));
}

// ---------------- kernel 6: 64 -> 1, -log ----------------
__global__ void ctx_loss_kernel(const float* __restrict__ blkmax,
                                float* __restrict__ out) {
    int tid = threadIdx.x;       // one wave of 64
    float best = blkmax[tid];
    for (int off = 32; off > 0; off >>= 1)
        best = fmaxf(best, __shfl_down(best, off, 64));
    if (tid == 0) out[0] = -logf(best);
}

extern "C" void kernel_launch(void* const* d_in, const int* in_sizes, int n_in,
                              void* d_out, int out_size, void* d_ws, size_t ws_size,
                              hipStream_t stream) {
    const float* inp = (const float*)d_in[0];
    const float* tgt = (const float*)d_in[1];
    float* out = (float*)d_out;

    // ws layout (bytes):
    //   xb     bf16 [16384][64]  2 MB
    //   tb     bf16 [16384][64]  2 MB
    //   pmin   f32  [32][16384]  2 MB
    //   pmax   f32  [32][16384]  2 MB
    //   psum   f32  [32][16384]  2 MB
    //   rmin   f32  [16384]      64 KB
    //   rmax   f32  [16384]      64 KB
    //   blkmax f32  [64]
    char* base = (char*)d_ws;
    short* xb     = (short*)(base);
    short* tb     = (short*)(base + (size_t)2 * NCOL * KPAD);           // +2MB
    float* pmin   = (float*)(base + (size_t)4 * NCOL * KPAD);           // +4MB
    float* pmax   = pmin + (size_t)JS * NCOL;
    float* psum   = pmax + (size_t)JS * NCOL;
    float* rmin   = psum + (size_t)JS * NCOL;
    float* rmax   = rmin + NCOL;
    float* blkmax = rmax + NCOL;

    dim3 grid2(NCOL / 256, JS);
    ctx_norm_kernel  <<<NCOL / 256, 256, 0, stream>>>(inp, tgt, xb, tb);
    ctx_stats_kernel <<<grid2, 256, 0, stream>>>(xb, tb, pmin, pmax);
    ctx_fold_kernel  <<<NCOL / 256, 256, 0, stream>>>(pmin, pmax, rmin, rmax);
    ctx_sumexp_kernel<<<grid2, 256, 0, stream>>>(xb, tb, rmin, psum);
    ctx_reduce_kernel<<<NCOL / 256, 256, 0, stream>>>(rmin, rmax, psum, blkmax);
    ctx_loss_kernel  <<<1, 64, 0, stream>>>(blkmax, out);
}